// Round 2
// baseline (521.990 us; speedup 1.0000x reference)
//
#include <hip/hip_runtime.h>
#include <hip/hip_bf16.h>

#define BATCH 16384
#define DIM   64
#define NNB   32
#define INDIM 4096          // 2 * NNB * DIM
#define BR    32            // batch rows per block
#define NBLK  (BATCH / BR)  // 512 blocks

typedef __attribute__((ext_vector_type(8))) short          s16x8;
typedef __attribute__((ext_vector_type(4))) float          f32x4;
typedef __attribute__((ext_vector_type(4))) unsigned short u16x4;

__device__ __forceinline__ float bf2f(unsigned short u) {
    union { unsigned int i; float f; } v;
    v.i = ((unsigned int)u) << 16;
    return v.f;
}

template<bool FP32>
__device__ __forceinline__ float ldT(const void* p, size_t i) {
    if constexpr (FP32) return ((const float*)p)[i];
    else                return bf2f(((const unsigned short*)p)[i]);
}

template<bool FP32>
__device__ __forceinline__ f32x4 ld4(const void* p, size_t i) {
    if constexpr (FP32) {
        return *(const f32x4*)((const float*)p + i);
    } else {
        const u16x4 v = *(const u16x4*)((const unsigned short*)p + i);
        f32x4 r;
        #pragma unroll
        for (int j = 0; j < 4; ++j) r[j] = bf2f(v[j]);
        return r;
    }
}

// split 8 f32 into bf16 hi (truncated) + bf16 lo (exact remainder, rounded)
__device__ __forceinline__ void split8(const f32x4 x, const f32x4 y, s16x8& h, s16x8& l) {
    #pragma unroll
    for (int j = 0; j < 8; ++j) {
        const float v = (j < 4) ? x[j] : y[j - 4];
        union { float f; unsigned u; } a, b, c;
        a.f = v;
        const unsigned short hh = (unsigned short)(a.u >> 16);
        b.u = ((unsigned)hh) << 16;
        c.f = v - b.f;
        h[j] = (short)hh;
        l[j] = (short)(c.u >> 16);
    }
}

// ws layout: [0:8) double loss accumulator (atomic fallback), [8:12) dtype flag,
//            [16:16+NBLK*8) per-block loss partials (if ws_size permits)
__global__ void kgnn_probe(const unsigned int* __restrict__ lab, int* __restrict__ flag) {
    if (threadIdx.x == 0) {
        int ok = 1;
        for (int i = 0; i < 32; ++i) {
            unsigned int w = lab[i];
            if (!(w == 0u || w == 0x3F800000u)) ok = 0;   // exactly 0.0f or 1.0f
        }
        *flag = ok;   // clean fp32 words -> fp32 problem; else bf16
    }
}

// Barrier-free direct-fragment MFMA GEMM.
// Block: BR=32 batch rows, 512 threads = 8 waves. Wave w: dt=w&3 (16 dims),
// kh=w>>2 (16 neighbors). Per wave: 2 row-tiles x 16 dims x K/2.
// A-frag (t_r) gathered straight from embedding tables per-lane:
//   lane: row = lane&15 (+rt*16), k = (lane>>4)*8 + j  -> 16B contiguous in emb row.
// B-frag from W row-major: lane: col dim = dt*16 + (lane&15), same k slice
//   -> 16B contiguous in W row. B-frags reused across both row-tiles.
// No __syncthreads in the K-loop; cross-wave (kh) reduce via LDS at the end.
template<bool FP32>
__global__ __launch_bounds__(512, 4) void kgnn_gemm(
    const int* __restrict__ users, const int* __restrict__ items,
    const void* __restrict__ label_, const int* __restrict__ nrel,
    const int* __restrict__ ntail,  const void* __restrict__ uemb_,
    const void* __restrict__ eemb_, const void* __restrict__ remb_,
    const void* __restrict__ W_,    const void* __restrict__ b_,
    double* __restrict__ acc, double* __restrict__ bsum,
    const int* __restrict__ flag, const int force)
{
    if (force < 0 && *flag != (FP32 ? 1 : 0)) return;   // fallback: wrong dtype exits

    __shared__ int   sidx[2][BR][NNB + 1];   // [rel/tail][row][n], +1 pad vs bank hits
    __shared__ float fl[2][BR][DIM];         // per-kh false_logit partials
    __shared__ float st[BR];

    const int t    = threadIdx.x;
    const int base = blockIdx.x * BR;
    const int lane = t & 63;
    const int w    = t >> 6;
    const int r16  = lane & 15;
    const int kg   = lane >> 4;
    const int dt   = w & 3;       // dim tile (16 dims)
    const int kh   = w >> 2;      // K half (16 neighbors)

    // stage neighbor indices (coalesced reads, conflict-free LDS writes)
    #pragma unroll
    for (int it = 0; it < 2; ++it) {
        const int e = it * 512 + t;          // 0..1023 = row*32 + n
        const int row = e >> 5, n = e & 31;
        sidx[0][row][n] = nrel [(size_t)base * NNB + e];
        sidx[1][row][n] = ntail[(size_t)base * NNB + e];
    }
    __syncthreads();

    f32x4 ac[2] = { {0.f,0.f,0.f,0.f}, {0.f,0.f,0.f,0.f} };
    const int dcol = dt * 16 + r16;

    if constexpr (!FP32) {
        const unsigned short* E  = (const unsigned short*)eemb_;
        const unsigned short* R  = (const unsigned short*)remb_;
        const unsigned short* wb = (const unsigned short*)W_ + (size_t)dcol * INDIM + kg * 8;
        #pragma unroll 2
        for (int nn = 0; nn < NNB / 2; ++nn) {
            const int n = kh * (NNB / 2) + nn;
            const unsigned short* wn = wb + n * 128;
            const s16x8 b0 = *(const s16x8*)(wn);
            const s16x8 b1 = *(const s16x8*)(wn + 32);
            const s16x8 b2 = *(const s16x8*)(wn + 64);
            const s16x8 b3 = *(const s16x8*)(wn + 96);
            #pragma unroll
            for (int rt = 0; rt < 2; ++rt) {
                const int ri = sidx[0][rt * 16 + r16][n];
                const int ti = sidx[1][rt * 16 + r16][n];
                const unsigned short* rr = R + (size_t)ri * DIM + kg * 8;
                const unsigned short* tr = E + (size_t)ti * DIM + kg * 8;
                const s16x8 a0 = *(const s16x8*)(rr);
                const s16x8 a1 = *(const s16x8*)(rr + 32);
                const s16x8 a2 = *(const s16x8*)(tr);
                const s16x8 a3 = *(const s16x8*)(tr + 32);
                ac[rt] = __builtin_amdgcn_mfma_f32_16x16x32_bf16(a0, b0, ac[rt], 0, 0, 0);
                ac[rt] = __builtin_amdgcn_mfma_f32_16x16x32_bf16(a1, b1, ac[rt], 0, 0, 0);
                ac[rt] = __builtin_amdgcn_mfma_f32_16x16x32_bf16(a2, b2, ac[rt], 0, 0, 0);
                ac[rt] = __builtin_amdgcn_mfma_f32_16x16x32_bf16(a3, b3, ac[rt], 0, 0, 0);
            }
        }
    } else {
        const float* E  = (const float*)eemb_;
        const float* R  = (const float*)remb_;
        const float* wb = (const float*)W_ + (size_t)dcol * INDIM + kg * 8;
        for (int nn = 0; nn < NNB / 2; ++nn) {
            const int n = kh * (NNB / 2) + nn;
            const float* wn = wb + n * 128;
            s16x8 bh[4], bl[4];
            #pragma unroll
            for (int s = 0; s < 4; ++s)
                split8(*(const f32x4*)(wn + s * 32), *(const f32x4*)(wn + s * 32 + 4),
                       bh[s], bl[s]);
            #pragma unroll
            for (int rt = 0; rt < 2; ++rt) {
                const int ri = sidx[0][rt * 16 + r16][n];
                const int ti = sidx[1][rt * 16 + r16][n];
                const float* rr = R + (size_t)ri * DIM + kg * 8;
                const float* tr = E + (size_t)ti * DIM + kg * 8;
                #pragma unroll
                for (int s = 0; s < 4; ++s) {
                    const float* ap = (s < 2) ? rr + s * 32 : tr + (s - 2) * 32;
                    s16x8 ah, al;
                    split8(*(const f32x4*)(ap), *(const f32x4*)(ap + 4), ah, al);
                    ac[rt] = __builtin_amdgcn_mfma_f32_16x16x32_bf16(ah, bh[s], ac[rt], 0, 0, 0);
                    ac[rt] = __builtin_amdgcn_mfma_f32_16x16x32_bf16(ah, bl[s], ac[rt], 0, 0, 0);
                    ac[rt] = __builtin_amdgcn_mfma_f32_16x16x32_bf16(al, bh[s], ac[rt], 0, 0, 0);
                }
            }
        }
    }

    // D layout (verified): col = lane&15, row-in-tile = (lane>>4)*4 + q
    #pragma unroll
    for (int rt = 0; rt < 2; ++rt) {
        #pragma unroll
        for (int q = 0; q < 4; ++q)
            fl[kh][rt * 16 + kg * 4 + q][dcol] = ac[rt][q];
    }
    __syncthreads();

    // epilogue: thread t -> row = t>>4 (0..31), c = t&15 -> dims c*4..c*4+3
    {
        const int row  = t >> 4;
        const int c    = t & 15;
        const int grow = base + row;
        const int uid  = users[grow], iid = items[grow];
        const f32x4 uv = ld4<FP32>(uemb_, (size_t)uid * DIM + c * 4);
        const f32x4 iv = ld4<FP32>(eemb_, (size_t)iid * DIM + c * 4);
        const f32x4 bv = ld4<FP32>(b_, (size_t)c * 4);
        float p1 = 0.f, p2 = 0.f;
        #pragma unroll
        for (int j = 0; j < 4; ++j) {
            const float lg = fl[0][row][c * 4 + j] + fl[1][row][c * 4 + j] + bv[j];
            const float fi = 1.f / (1.f + expf(-lg));        // false_item[d]
            p2 += uv[j] * fi;
            p1 += uv[j] * iv[j];
        }
        #pragma unroll
        for (int m = 1; m < 16; m <<= 1) {
            p1 += __shfl_xor(p1, m, 16);
            p2 += __shfl_xor(p2, m, 16);
        }
        if (c == 0) {
            const float y  = ldT<FP32>(label_, grow);
            const float pa = 1.f / (1.f + expf(-p1));
            const float pb = 1.f / (1.f + expf(-p2));
            st[row] =
                  y * fmaxf(logf(pa), -100.f) + (1.f - y) * fmaxf(log1pf(-pa), -100.f)
                + y * fmaxf(logf(pb), -100.f) + (1.f - y) * fmaxf(log1pf(-pb), -100.f);
        }
    }
    __syncthreads();

    if (t < 64) {
        float s = (t < BR) ? st[t] : 0.f;
        #pragma unroll
        for (int m = 1; m < 64; m <<= 1) s += __shfl_xor(s, m, 64);
        if (t == 0) {
            if (bsum) bsum[blockIdx.x] = (double)s;   // deterministic per-block slot
            else      atomicAdd(acc, (double)s);      // tiny-ws fallback
        }
    }
}

__global__ void kgnn_fin(const double* __restrict__ acc, const double* __restrict__ bsum,
                         const int* __restrict__ flag, void* __restrict__ out,
                         const int mode) {
    __shared__ double sd[4];
    const int t = threadIdx.x;
    double s = 0.0;
    if (bsum) {
        for (int i = t; i < NBLK; i += 256) s += bsum[i];
    } else if (t == 0) {
        s = *acc;
    }
    #pragma unroll
    for (int m = 1; m < 64; m <<= 1) s += __shfl_xor(s, m, 64);
    if ((t & 63) == 0) sd[t >> 6] = s;
    __syncthreads();
    if (t == 0) {
        const double tot = sd[0] + sd[1] + sd[2] + sd[3];
        const int md = (mode < 0) ? *flag : mode;
        const float loss = (float)(-tot / (double)BATCH);
        if (md) ((float*)out)[0] = loss;
        else    ((__hip_bfloat16*)out)[0] = __float2bfloat16(loss);
    }
}

extern "C" void kernel_launch(void* const* d_in, const int* in_sizes, int n_in,
                              void* d_out, int out_size, void* d_ws, size_t ws_size,
                              hipStream_t stream) {
    const int* users = (const int*)d_in[0];
    const int* items = (const int*)d_in[1];
    const void* label = d_in[2];
    const int* nrel  = (const int*)d_in[3];
    const int* ntail = (const int*)d_in[4];
    const void* uemb = d_in[5];
    const void* eemb = d_in[6];
    const void* remb = d_in[7];
    const void* genW = d_in[8];
    const void* genb = d_in[9];

    double* acc  = (double*)d_ws;
    int*    flag = (int*)((char*)d_ws + 8);
    double* bsum = (ws_size >= (size_t)(16 + NBLK * 8))
                       ? (double*)((char*)d_ws + 16) : nullptr;
    hipMemsetAsync(d_ws, 0, 16, stream);

    // dtype: out_size (2B bf16 / 4B fp32 scalar) + user_emb byte-size agreement.
    // Decisive -> single forced launch; else probe + both variants (one exits early).
    const bool f32sz  = (out_size == 4) && (in_sizes[5] == 128000000);
    const bool bf16sz = (out_size == 2) && (in_sizes[5] == 64000000);

    if (f32sz) {
        kgnn_gemm<true><<<NBLK, 512, 0, stream>>>(
            users, items, label, nrel, ntail, uemb, eemb, remb, genW, genb,
            acc, bsum, flag, 1);
        kgnn_fin<<<1, 256, 0, stream>>>(acc, bsum, flag, d_out, 1);
    } else if (bf16sz) {
        kgnn_gemm<false><<<NBLK, 512, 0, stream>>>(
            users, items, label, nrel, ntail, uemb, eemb, remb, genW, genb,
            acc, bsum, flag, 0);
        kgnn_fin<<<1, 256, 0, stream>>>(acc, bsum, flag, d_out, 0);
    } else {
        kgnn_probe<<<1, 64, 0, stream>>>((const unsigned int*)label, flag);
        kgnn_gemm<false><<<NBLK, 512, 0, stream>>>(
            users, items, label, nrel, ntail, uemb, eemb, remb, genW, genb,
            acc, bsum, flag, -1);
        kgnn_gemm<true><<<NBLK, 512, 0, stream>>>(
            users, items, label, nrel, ntail, uemb, eemb, remb, genW, genb,
            acc, bsum, flag, -1);
        kgnn_fin<<<1, 256, 0, stream>>>(acc, bsum, flag, d_out, -1);
    }
}

// Round 3
// 509.900 us; speedup vs baseline: 1.0237x; 1.0237x over previous
//
#include <hip/hip_runtime.h>
#include <hip/hip_bf16.h>

#define BATCH 16384
#define DIM   64
#define NNB   32
#define INDIM 4096          // 2 * NNB * DIM
#define BR    16            // batch rows per block
#define WPB   4             // waves per block
#define NPW   (NNB / WPB)   // neighbors per wave = 8
#define NBLK  (BATCH / BR)  // 1024 blocks

typedef __attribute__((ext_vector_type(8))) short          s16x8;
typedef __attribute__((ext_vector_type(4))) float          f32x4;
typedef __attribute__((ext_vector_type(4))) unsigned short u16x4;

__device__ __forceinline__ float bf2f(unsigned short u) {
    union { unsigned int i; float f; } v;
    v.i = ((unsigned int)u) << 16;
    return v.f;
}

template<bool FP32>
__device__ __forceinline__ float ldT(const void* p, size_t i) {
    if constexpr (FP32) return ((const float*)p)[i];
    else                return bf2f(((const unsigned short*)p)[i]);
}

template<bool FP32>
__device__ __forceinline__ f32x4 ld4(const void* p, size_t i) {
    if constexpr (FP32) {
        return *(const f32x4*)((const float*)p + i);
    } else {
        const u16x4 v = *(const u16x4*)((const unsigned short*)p + i);
        f32x4 r;
        #pragma unroll
        for (int j = 0; j < 4; ++j) r[j] = bf2f(v[j]);
        return r;
    }
}

// split 8 f32 into bf16 hi (truncated) + bf16 lo (exact remainder, rounded)
__device__ __forceinline__ void split8(const f32x4 x, const f32x4 y, s16x8& h, s16x8& l) {
    #pragma unroll
    for (int j = 0; j < 8; ++j) {
        const float v = (j < 4) ? x[j] : y[j - 4];
        union { float f; unsigned u; } a, b, c;
        a.f = v;
        const unsigned short hh = (unsigned short)(a.u >> 16);
        b.u = ((unsigned)hh) << 16;
        c.f = v - b.f;
        h[j] = (short)hh;
        l[j] = (short)(c.u >> 16);
    }
}

// ws layout: [0:8) double loss acc (atomic fallback), [8:12) dtype flag,
//            [16:16+NBLK*8) per-block loss partials (if ws_size permits)
__global__ void kgnn_probe(const unsigned int* __restrict__ lab, int* __restrict__ flag) {
    if (threadIdx.x == 0) {
        int ok = 1;
        for (int i = 0; i < 32; ++i) {
            unsigned int w = lab[i];
            if (!(w == 0u || w == 0x3F800000u)) ok = 0;   // exactly 0.0f or 1.0f
        }
        *flag = ok;   // clean fp32 words -> fp32 problem; else bf16
    }
}

// K-split barrier-free MFMA GEMM.
// Block: BR=16 rows, 256 threads = 4 waves. Wave w owns neighbors n = w*8..w*8+7
// and computes ALL 16 rows x 64 dims (4 acc tiles) for its K-range -> every
// gathered entity row loaded exactly once per block (no dt redundancy).
// Indices live in registers (2 ints/table/lane), distributed per-neighbor by shfl
// -> no LDS, no barrier in the K-loop. One barrier for the cross-wave K-reduce.
// A-frag: lane row = lane&15, k = (lane>>4)*8+j -> 16B contiguous in emb row.
// B-frag: lane col = dt*16 + (lane&15), same k slice -> 16B contiguous in W row.
template<bool FP32>
__global__ __launch_bounds__(256, 4) void kgnn_gemm(
    const int* __restrict__ users, const int* __restrict__ items,
    const void* __restrict__ label_, const int* __restrict__ nrel,
    const int* __restrict__ ntail,  const void* __restrict__ uemb_,
    const void* __restrict__ eemb_, const void* __restrict__ remb_,
    const void* __restrict__ W_,    const void* __restrict__ b_,
    double* __restrict__ acc, double* __restrict__ bsum,
    const int* __restrict__ flag, const int force)
{
    if (force < 0 && *flag != (FP32 ? 1 : 0)) return;   // fallback: wrong dtype exits

    __shared__ float fl[WPB][BR][68];    // padded stride: conflict-free stores
    __shared__ float st[BR];

    const int t    = threadIdx.x;
    const int base = blockIdx.x * BR;
    const int lane = t & 63;
    const int w    = t >> 6;        // wave 0..3
    const int r16  = lane & 15;
    const int kg   = lane >> 4;     // 0..3
    const int n0   = w * NPW;

    // preload this wave's neighbor indices: lane (r16,kg) holds q = kg and q = kg+4
    int pr0, pr1, pt0, pt1;
    {
        const size_t rb = (size_t)(base + r16) * NNB + n0;
        pr0 = nrel [rb + kg];
        pr1 = nrel [rb + 4 + kg];
        pt0 = ntail[rb + kg];
        pt1 = ntail[rb + 4 + kg];
    }

    f32x4 ac[4] = { {0,0,0,0}, {0,0,0,0}, {0,0,0,0}, {0,0,0,0} };

    if constexpr (!FP32) {
        const unsigned short* E = (const unsigned short*)eemb_;
        const unsigned short* R = (const unsigned short*)remb_;
        const unsigned short* W = (const unsigned short*)W_;
        #pragma unroll 2
        for (int q = 0; q < NPW; ++q) {
            const int n    = n0 + q;
            const int ridx = __shfl((q & 4) ? pr1 : pr0, r16 + 16 * (q & 3), 64);
            const int tidx = __shfl((q & 4) ? pt1 : pt0, r16 + 16 * (q & 3), 64);
            const unsigned short* rr = R + (size_t)ridx * DIM + kg * 8;
            const unsigned short* tr = E + (size_t)tidx * DIM + kg * 8;
            const s16x8 a0 = *(const s16x8*)(rr);
            const s16x8 a1 = *(const s16x8*)(rr + 32);
            const s16x8 a2 = *(const s16x8*)(tr);
            const s16x8 a3 = *(const s16x8*)(tr + 32);
            const unsigned short* wq = W + (size_t)r16 * INDIM + n * 128 + kg * 8;
            #pragma unroll
            for (int dt = 0; dt < 4; ++dt) {
                const unsigned short* wd = wq + (size_t)dt * 16 * INDIM;
                const s16x8 b0 = *(const s16x8*)(wd);
                const s16x8 b1 = *(const s16x8*)(wd + 32);
                const s16x8 b2 = *(const s16x8*)(wd + 64);
                const s16x8 b3 = *(const s16x8*)(wd + 96);
                ac[dt] = __builtin_amdgcn_mfma_f32_16x16x32_bf16(a0, b0, ac[dt], 0, 0, 0);
                ac[dt] = __builtin_amdgcn_mfma_f32_16x16x32_bf16(a1, b1, ac[dt], 0, 0, 0);
                ac[dt] = __builtin_amdgcn_mfma_f32_16x16x32_bf16(a2, b2, ac[dt], 0, 0, 0);
                ac[dt] = __builtin_amdgcn_mfma_f32_16x16x32_bf16(a3, b3, ac[dt], 0, 0, 0);
            }
        }
    } else {
        const float* E = (const float*)eemb_;
        const float* R = (const float*)remb_;
        const float* W = (const float*)W_;
        #pragma unroll 2
        for (int q = 0; q < NPW; ++q) {
            const int n    = n0 + q;
            const int ridx = __shfl((q & 4) ? pr1 : pr0, r16 + 16 * (q & 3), 64);
            const int tidx = __shfl((q & 4) ? pt1 : pt0, r16 + 16 * (q & 3), 64);
            const float* rr = R + (size_t)ridx * DIM + kg * 8;
            const float* tr = E + (size_t)tidx * DIM + kg * 8;
            s16x8 ah[4], al[4];
            #pragma unroll
            for (int s = 0; s < 4; ++s) {
                const float* ap = (s < 2) ? rr + s * 32 : tr + (s - 2) * 32;
                split8(*(const f32x4*)(ap), *(const f32x4*)(ap + 4), ah[s], al[s]);
            }
            const float* wq = W + (size_t)r16 * INDIM + n * 128 + kg * 8;
            #pragma unroll
            for (int dt = 0; dt < 4; ++dt) {
                const float* wd = wq + (size_t)dt * 16 * INDIM;
                #pragma unroll
                for (int s = 0; s < 4; ++s) {
                    s16x8 bh, bl;
                    split8(*(const f32x4*)(wd + s * 32), *(const f32x4*)(wd + s * 32 + 4),
                           bh, bl);
                    ac[dt] = __builtin_amdgcn_mfma_f32_16x16x32_bf16(ah[s], bh, ac[dt], 0, 0, 0);
                    ac[dt] = __builtin_amdgcn_mfma_f32_16x16x32_bf16(ah[s], bl, ac[dt], 0, 0, 0);
                    ac[dt] = __builtin_amdgcn_mfma_f32_16x16x32_bf16(al[s], bh, ac[dt], 0, 0, 0);
                }
            }
        }
    }

    // D layout (verified r2): col = lane&15, row = (lane>>4)*4 + reg
    #pragma unroll
    for (int dt = 0; dt < 4; ++dt)
        #pragma unroll
        for (int qq = 0; qq < 4; ++qq)
            fl[w][kg * 4 + qq][dt * 16 + r16] = ac[dt][qq];
    __syncthreads();

    // epilogue: thread t -> row = t>>4 (0..15), c = t&15 -> dims c*4..c*4+3
    {
        const int row  = t >> 4;
        const int c    = t & 15;
        const int grow = base + row;
        const int uid  = users[grow], iid = items[grow];
        const f32x4 uv = ld4<FP32>(uemb_, (size_t)uid * DIM + c * 4);
        const f32x4 iv = ld4<FP32>(eemb_, (size_t)iid * DIM + c * 4);
        const f32x4 bv = ld4<FP32>(b_, (size_t)c * 4);
        float p1 = 0.f, p2 = 0.f;
        #pragma unroll
        for (int j = 0; j < 4; ++j) {
            const int d = c * 4 + j;
            const float lg = fl[0][row][d] + fl[1][row][d]
                           + fl[2][row][d] + fl[3][row][d] + bv[j];
            const float fi = 1.f / (1.f + expf(-lg));        // false_item[d]
            p2 += uv[j] * fi;
            p1 += uv[j] * iv[j];
        }
        #pragma unroll
        for (int m = 1; m < 16; m <<= 1) {
            p1 += __shfl_xor(p1, m, 16);
            p2 += __shfl_xor(p2, m, 16);
        }
        if (c == 0) {
            const float y  = ldT<FP32>(label_, grow);
            const float pa = 1.f / (1.f + expf(-p1));
            const float pb = 1.f / (1.f + expf(-p2));
            st[row] =
                  y * fmaxf(logf(pa), -100.f) + (1.f - y) * fmaxf(log1pf(-pa), -100.f)
                + y * fmaxf(logf(pb), -100.f) + (1.f - y) * fmaxf(log1pf(-pb), -100.f);
        }
    }
    __syncthreads();

    if (t < 64) {
        float s = (t < BR) ? st[t] : 0.f;
        #pragma unroll
        for (int m = 1; m < 64; m <<= 1) s += __shfl_xor(s, m, 64);
        if (t == 0) {
            if (bsum) bsum[blockIdx.x] = (double)s;   // deterministic per-block slot
            else      atomicAdd(acc, (double)s);      // tiny-ws fallback
        }
    }
}

__global__ void kgnn_fin(const double* __restrict__ acc, const double* __restrict__ bsum,
                         const int* __restrict__ flag, void* __restrict__ out,
                         const int mode) {
    __shared__ double sd[4];
    const int t = threadIdx.x;
    double s = 0.0;
    if (bsum) {
        for (int i = t; i < NBLK; i += 256) s += bsum[i];
    } else if (t == 0) {
        s = *acc;
    }
    #pragma unroll
    for (int m = 1; m < 64; m <<= 1) s += __shfl_xor(s, m, 64);
    if ((t & 63) == 0) sd[t >> 6] = s;
    __syncthreads();
    if (t == 0) {
        const double tot = sd[0] + sd[1] + sd[2] + sd[3];
        const int md = (mode < 0) ? *flag : mode;
        const float loss = (float)(-tot / (double)BATCH);
        if (md) ((float*)out)[0] = loss;
        else    ((__hip_bfloat16*)out)[0] = __float2bfloat16(loss);
    }
}

extern "C" void kernel_launch(void* const* d_in, const int* in_sizes, int n_in,
                              void* d_out, int out_size, void* d_ws, size_t ws_size,
                              hipStream_t stream) {
    const int* users = (const int*)d_in[0];
    const int* items = (const int*)d_in[1];
    const void* label = d_in[2];
    const int* nrel  = (const int*)d_in[3];
    const int* ntail = (const int*)d_in[4];
    const void* uemb = d_in[5];
    const void* eemb = d_in[6];
    const void* remb = d_in[7];
    const void* genW = d_in[8];
    const void* genb = d_in[9];

    double* acc  = (double*)d_ws;
    int*    flag = (int*)((char*)d_ws + 8);
    double* bsum = (ws_size >= (size_t)(16 + NBLK * 8))
                       ? (double*)((char*)d_ws + 16) : nullptr;
    hipMemsetAsync(d_ws, 0, 16, stream);

    // dtype: out_size (2B bf16 / 4B fp32 scalar) + user_emb byte-size agreement.
    const bool f32sz  = (out_size == 4) && (in_sizes[5] == 128000000);
    const bool bf16sz = (out_size == 2) && (in_sizes[5] == 64000000);

    if (f32sz) {
        kgnn_gemm<true><<<NBLK, 256, 0, stream>>>(
            users, items, label, nrel, ntail, uemb, eemb, remb, genW, genb,
            acc, bsum, flag, 1);
        kgnn_fin<<<1, 256, 0, stream>>>(acc, bsum, flag, d_out, 1);
    } else if (bf16sz) {
        kgnn_gemm<false><<<NBLK, 256, 0, stream>>>(
            users, items, label, nrel, ntail, uemb, eemb, remb, genW, genb,
            acc, bsum, flag, 0);
        kgnn_fin<<<1, 256, 0, stream>>>(acc, bsum, flag, d_out, 0);
    } else {
        kgnn_probe<<<1, 64, 0, stream>>>((const unsigned int*)label, flag);
        kgnn_gemm<false><<<NBLK, 256, 0, stream>>>(
            users, items, label, nrel, ntail, uemb, eemb, remb, genW, genb,
            acc, bsum, flag, -1);
        kgnn_gemm<true><<<NBLK, 256, 0, stream>>>(
            users, items, label, nrel, ntail, uemb, eemb, remb, genW, genb,
            acc, bsum, flag, -1);
        kgnn_fin<<<1, 256, 0, stream>>>(acc, bsum, flag, d_out, -1);
    }
}

// Round 4
// 430.661 us; speedup vs baseline: 1.2121x; 1.1840x over previous
//
#include <hip/hip_runtime.h>
#include <hip/hip_bf16.h>

#define BATCH 16384
#define DIM   64
#define NNB   32
#define INDIM 4096          // 2 * NNB * DIM
#define RPB   128           // batch rows per kgnn_part block
#define EPB   1024          // epilogue blocks (= BATCH/16) == bsum slots

typedef __attribute__((ext_vector_type(8))) short          s16x8;
typedef __attribute__((ext_vector_type(4))) float          f32x4;
typedef __attribute__((ext_vector_type(4))) unsigned int   u32x4;
typedef __attribute__((ext_vector_type(4))) unsigned short u16x4;

__device__ __forceinline__ float bf2f(unsigned short u) {
    union { unsigned int i; float f; } v;
    v.i = ((unsigned int)u) << 16;
    return v.f;
}

template<bool FP32>
__device__ __forceinline__ float ldT(const void* p, size_t i) {
    if constexpr (FP32) return ((const float*)p)[i];
    else                return bf2f(((const unsigned short*)p)[i]);
}

template<bool FP32>
__device__ __forceinline__ f32x4 ld4(const void* p, size_t i) {
    if constexpr (FP32) {
        return *(const f32x4*)((const float*)p + i);
    } else {
        const u16x4 v = *(const u16x4*)((const unsigned short*)p + i);
        f32x4 r;
        #pragma unroll
        for (int j = 0; j < 4; ++j) r[j] = bf2f(v[j]);
        return r;
    }
}

// split 8 f32 into bf16 hi (truncated) + bf16 lo (exact remainder, rounded)
__device__ __forceinline__ void split8(const f32x4 x, const f32x4 y, s16x8& h, s16x8& l) {
    #pragma unroll
    for (int j = 0; j < 8; ++j) {
        const float v = (j < 4) ? x[j] : y[j - 4];
        union { float f; unsigned u; } a, b, c;
        a.f = v;
        const unsigned short hh = (unsigned short)(a.u >> 16);
        b.u = ((unsigned)hh) << 16;
        c.f = v - b.f;
        h[j] = (short)hh;
        l[j] = (short)(c.u >> 16);
    }
}

// ws layout: [0:8) double acc (atomic fallback), [8:12) dtype flag,
//            [1024:1024+EPB*8) per-block loss partials,
//            [16384: ...) split-K logit partials (f32)
__global__ void kgnn_probe(const unsigned int* __restrict__ lab, int* __restrict__ flag) {
    if (threadIdx.x == 0) {
        int ok = 1;
        for (int i = 0; i < 32; ++i) {
            unsigned int w = lab[i];
            if (!(w == 0u || w == 0x3F800000u)) ok = 0;   // exactly 0.0f or 1.0f
        }
        *flag = ok;   // clean fp32 words -> fp32 problem; else bf16
    }
}

// Split-K MFMA partial-GEMM. Grid = (BATCH/RPB) x NSLICE.
// Block: 512 thr = 8 waves; slice = bid & (NS-1); rows = rtile*128 .. +128.
// W k-slice (NSL neighbors) staged ONCE into LDS, coalesced, T2 XOR-swizzled
// (byte ^= (dim&7)<<4 per 16B granule). Wave w owns rows w*16..w*16+15, all 64
// dims. K-loop barrier-free: A-frags gathered per-lane (compulsory lines only),
// B-frags from LDS ds_read_b128 (conflict-free). Partials -> ws (f32).
// fp32: W staged as hi/lo bf16 (3-product MFMA), NSL=2.
template<bool FP32>
__global__ __launch_bounds__(512, 4) void kgnn_part(
    const int* __restrict__ nrel, const int* __restrict__ ntail,
    const void* __restrict__ eemb_, const void* __restrict__ remb_,
    const void* __restrict__ W_,
    float* __restrict__ part, const int* __restrict__ flag, const int force)
{
    if (force < 0 && *flag != (FP32 ? 1 : 0)) return;

    constexpr int NSL = FP32 ? 2 : 4;     // neighbors per slice
    constexpr int NS  = FP32 ? 16 : 8;    // slices
    __shared__ __align__(16) unsigned char ldsW[65536];

    const int t     = threadIdx.x;
    const int bid   = blockIdx.x;
    const int slice = bid & (NS - 1);
    const int rtile = bid / NS;
    const int base  = rtile * RPB;
    const int lane  = t & 63;
    const int w     = t >> 6;
    const int r16   = lane & 15;
    const int kg    = lane >> 4;
    const int sw    = (r16 & 7) << 4;

    // ---- stage W slice -> LDS [64 dims][1024 B], swizzled ----
    if constexpr (!FP32) {
        const unsigned char* Wb = (const unsigned char*)W_;
        #pragma unroll
        for (int i = 0; i < 8; ++i) {
            const int e = i * 512 + t;            // 4096 x 16B = 64 KB
            const int dim = e >> 6, ko = (e & 63) * 16;
            const u32x4 v = *(const u32x4*)(Wb + (size_t)dim * 8192 + slice * 1024 + ko);
            *(u32x4*)&ldsW[dim * 1024 + (ko ^ ((dim & 7) << 4))] = v;
        }
    } else {
        const float* Wf = (const float*)W_;
        #pragma unroll
        for (int i = 0; i < 4; ++i) {
            const int e = i * 512 + t;            // 2048 x 8 floats = 64 KB src
            const int dim = e >> 5, g = e & 31;
            const float* src = Wf + (size_t)dim * INDIM + slice * 256 + g * 8;
            s16x8 h, l;
            split8(*(const f32x4*)src, *(const f32x4*)(src + 4), h, l);
            const int swd = (dim & 7) << 4;
            *(s16x8*)&ldsW[dim * 1024 + ((g * 16) ^ swd)]       = h;
            *(s16x8*)&ldsW[dim * 1024 + ((512 + g * 16) ^ swd)] = l;
        }
    }

    // index preload: lane (r16,kg) holds neighbor slice*NSL + (kg % NSL) of its row
    const size_t rb = (size_t)(base + w * 16 + r16) * NNB + slice * NSL;
    const int pr = nrel [rb + (kg % NSL)];
    const int pt = ntail[rb + (kg % NSL)];

    __syncthreads();

    f32x4 ac[4] = { {0,0,0,0}, {0,0,0,0}, {0,0,0,0}, {0,0,0,0} };

    if constexpr (!FP32) {
        const unsigned short* E = (const unsigned short*)eemb_;
        const unsigned short* R = (const unsigned short*)remb_;
        #pragma unroll 2
        for (int q = 0; q < NSL; ++q) {
            const int ridx = __shfl(pr, r16 + 16 * q, 64);
            const int tidx = __shfl(pt, r16 + 16 * q, 64);
            const unsigned short* rr = R + (size_t)ridx * DIM + kg * 8;
            const unsigned short* tr = E + (size_t)tidx * DIM + kg * 8;
            s16x8 a[4];
            a[0] = *(const s16x8*)(rr);
            a[1] = *(const s16x8*)(rr + 32);
            a[2] = *(const s16x8*)(tr);
            a[3] = *(const s16x8*)(tr + 32);
            #pragma unroll
            for (int dt = 0; dt < 4; ++dt) {
                const int rowb = (dt * 16 + r16) * 1024;
                #pragma unroll
                for (int ks = 0; ks < 4; ++ks) {
                    const s16x8 b = *(const s16x8*)
                        &ldsW[rowb + ((q * 256 + ks * 64 + kg * 16) ^ sw)];
                    ac[dt] = __builtin_amdgcn_mfma_f32_16x16x32_bf16(a[ks], b, ac[dt], 0, 0, 0);
                }
            }
        }
    } else {
        const float* E = (const float*)eemb_;
        const float* R = (const float*)remb_;
        #pragma unroll
        for (int q = 0; q < NSL; ++q) {
            const int ridx = __shfl(pr, r16 + 16 * q, 64);
            const int tidx = __shfl(pt, r16 + 16 * q, 64);
            const float* rr = R + (size_t)ridx * DIM + kg * 8;
            const float* tr = E + (size_t)tidx * DIM + kg * 8;
            s16x8 ah[4], al[4];
            #pragma unroll
            for (int s = 0; s < 4; ++s) {
                const float* ap = (s < 2) ? rr + s * 32 : tr + (s - 2) * 32;
                split8(*(const f32x4*)(ap), *(const f32x4*)(ap + 4), ah[s], al[s]);
            }
            #pragma unroll
            for (int dt = 0; dt < 4; ++dt) {
                const int rowb = (dt * 16 + r16) * 1024;
                #pragma unroll
                for (int ks = 0; ks < 4; ++ks) {
                    const int ko = q * 256 + ks * 64 + kg * 16;
                    const s16x8 bh = *(const s16x8*)&ldsW[rowb + (ko ^ sw)];
                    const s16x8 bl = *(const s16x8*)&ldsW[rowb + ((512 + ko) ^ sw)];
                    ac[dt] = __builtin_amdgcn_mfma_f32_16x16x32_bf16(ah[ks], bh, ac[dt], 0, 0, 0);
                    ac[dt] = __builtin_amdgcn_mfma_f32_16x16x32_bf16(ah[ks], bl, ac[dt], 0, 0, 0);
                    ac[dt] = __builtin_amdgcn_mfma_f32_16x16x32_bf16(al[ks], bh, ac[dt], 0, 0, 0);
                }
            }
        }
    }

    // D layout (verified): col = lane&15, row = (lane>>4)*4 + reg
    #pragma unroll
    for (int dt = 0; dt < 4; ++dt)
        #pragma unroll
        for (int qq = 0; qq < 4; ++qq) {
            const int row = base + w * 16 + kg * 4 + qq;
            part[((size_t)row * NS + slice) * 64 + dt * 16 + r16] = ac[dt][qq];
        }
}

// Epilogue: reduce slices, bias, sigmoid, dots, BCE. Grid = EPB (16 rows/block).
template<bool FP32>
__global__ void kgnn_epi(
    const int* __restrict__ users, const int* __restrict__ items,
    const void* __restrict__ label_, const void* __restrict__ uemb_,
    const void* __restrict__ eemb_, const void* __restrict__ b_,
    const float* __restrict__ part, double* __restrict__ bsum,
    const int* __restrict__ flag, const int force)
{
    if (force < 0 && *flag != (FP32 ? 1 : 0)) return;
    constexpr int NS = FP32 ? 16 : 8;
    __shared__ float st[16];

    const int t   = threadIdx.x;
    const int row = blockIdx.x * 16 + (t >> 4);
    const int c   = t & 15;

    f32x4 fs = {0.f, 0.f, 0.f, 0.f};
    #pragma unroll
    for (int sl = 0; sl < NS; ++sl)
        fs += *(const f32x4*)(part + ((size_t)row * NS + sl) * 64 + c * 4);

    const int uid = users[row], iid = items[row];
    const f32x4 uv = ld4<FP32>(uemb_, (size_t)uid * DIM + c * 4);
    const f32x4 iv = ld4<FP32>(eemb_, (size_t)iid * DIM + c * 4);
    const f32x4 bv = ld4<FP32>(b_, (size_t)c * 4);
    float p1 = 0.f, p2 = 0.f;
    #pragma unroll
    for (int j = 0; j < 4; ++j) {
        const float fi = 1.f / (1.f + expf(-(fs[j] + bv[j])));   // false_item[d]
        p2 += uv[j] * fi;
        p1 += uv[j] * iv[j];
    }
    #pragma unroll
    for (int m = 1; m < 16; m <<= 1) {
        p1 += __shfl_xor(p1, m, 16);
        p2 += __shfl_xor(p2, m, 16);
    }
    if (c == 0) {
        const float y  = ldT<FP32>(label_, row);
        const float pa = 1.f / (1.f + expf(-p1));
        const float pb = 1.f / (1.f + expf(-p2));
        st[t >> 4] =
              y * fmaxf(logf(pa), -100.f) + (1.f - y) * fmaxf(log1pf(-pa), -100.f)
            + y * fmaxf(logf(pb), -100.f) + (1.f - y) * fmaxf(log1pf(-pb), -100.f);
    }
    __syncthreads();
    if (t < 64) {
        float s = (t < 16) ? st[t] : 0.f;
        #pragma unroll
        for (int m = 1; m < 64; m <<= 1) s += __shfl_xor(s, m, 64);
        if (t == 0) bsum[blockIdx.x] = (double)s;
    }
}

// ---- fallback (R3 monolithic) for tiny-ws / unexpected shapes ----
template<bool FP32>
__global__ __launch_bounds__(256, 4) void kgnn_fb(
    const int* __restrict__ users, const int* __restrict__ items,
    const void* __restrict__ label_, const int* __restrict__ nrel,
    const int* __restrict__ ntail,  const void* __restrict__ uemb_,
    const void* __restrict__ eemb_, const void* __restrict__ remb_,
    const void* __restrict__ W_,    const void* __restrict__ b_,
    double* __restrict__ acc, double* __restrict__ bsum,
    const int* __restrict__ flag, const int force)
{
    if (force < 0 && *flag != (FP32 ? 1 : 0)) return;
    __shared__ float fl[4][16][68];
    __shared__ float st[16];
    const int t = threadIdx.x, base = blockIdx.x * 16;
    const int lane = t & 63, w = t >> 6, r16 = lane & 15, kg = lane >> 4;
    const int n0 = w * 8;
    int pr0, pr1, pt0, pt1;
    {
        const size_t rb = (size_t)(base + r16) * NNB + n0;
        pr0 = nrel[rb + kg];  pr1 = nrel[rb + 4 + kg];
        pt0 = ntail[rb + kg]; pt1 = ntail[rb + 4 + kg];
    }
    f32x4 ac[4] = { {0,0,0,0}, {0,0,0,0}, {0,0,0,0}, {0,0,0,0} };
    if constexpr (!FP32) {
        const unsigned short* E = (const unsigned short*)eemb_;
        const unsigned short* R = (const unsigned short*)remb_;
        const unsigned short* W = (const unsigned short*)W_;
        #pragma unroll 2
        for (int q = 0; q < 8; ++q) {
            const int n = n0 + q;
            const int ridx = __shfl((q & 4) ? pr1 : pr0, r16 + 16 * (q & 3), 64);
            const int tidx = __shfl((q & 4) ? pt1 : pt0, r16 + 16 * (q & 3), 64);
            const unsigned short* rr = R + (size_t)ridx * DIM + kg * 8;
            const unsigned short* tr = E + (size_t)tidx * DIM + kg * 8;
            const s16x8 a0 = *(const s16x8*)(rr),      a1 = *(const s16x8*)(rr + 32);
            const s16x8 a2 = *(const s16x8*)(tr),      a3 = *(const s16x8*)(tr + 32);
            const unsigned short* wq = W + (size_t)r16 * INDIM + n * 128 + kg * 8;
            #pragma unroll
            for (int dt = 0; dt < 4; ++dt) {
                const unsigned short* wd = wq + (size_t)dt * 16 * INDIM;
                ac[dt] = __builtin_amdgcn_mfma_f32_16x16x32_bf16(a0, *(const s16x8*)(wd),      ac[dt], 0, 0, 0);
                ac[dt] = __builtin_amdgcn_mfma_f32_16x16x32_bf16(a1, *(const s16x8*)(wd + 32), ac[dt], 0, 0, 0);
                ac[dt] = __builtin_amdgcn_mfma_f32_16x16x32_bf16(a2, *(const s16x8*)(wd + 64), ac[dt], 0, 0, 0);
                ac[dt] = __builtin_amdgcn_mfma_f32_16x16x32_bf16(a3, *(const s16x8*)(wd + 96), ac[dt], 0, 0, 0);
            }
        }
    } else {
        const float* E = (const float*)eemb_;
        const float* R = (const float*)remb_;
        const float* W = (const float*)W_;
        #pragma unroll 2
        for (int q = 0; q < 8; ++q) {
            const int n = n0 + q;
            const int ridx = __shfl((q & 4) ? pr1 : pr0, r16 + 16 * (q & 3), 64);
            const int tidx = __shfl((q & 4) ? pt1 : pt0, r16 + 16 * (q & 3), 64);
            const float* rr = R + (size_t)ridx * DIM + kg * 8;
            const float* tr = E + (size_t)tidx * DIM + kg * 8;
            s16x8 ah[4], al[4];
            #pragma unroll
            for (int s = 0; s < 4; ++s) {
                const float* ap = (s < 2) ? rr + s * 32 : tr + (s - 2) * 32;
                split8(*(const f32x4*)(ap), *(const f32x4*)(ap + 4), ah[s], al[s]);
            }
            const float* wq = W + (size_t)r16 * INDIM + n * 128 + kg * 8;
            #pragma unroll
            for (int dt = 0; dt < 4; ++dt) {
                const float* wd = wq + (size_t)dt * 16 * INDIM;
                #pragma unroll
                for (int s = 0; s < 4; ++s) {
                    s16x8 bh, bl;
                    split8(*(const f32x4*)(wd + s * 32), *(const f32x4*)(wd + s * 32 + 4), bh, bl);
                    ac[dt] = __builtin_amdgcn_mfma_f32_16x16x32_bf16(ah[s], bh, ac[dt], 0, 0, 0);
                    ac[dt] = __builtin_amdgcn_mfma_f32_16x16x32_bf16(ah[s], bl, ac[dt], 0, 0, 0);
                    ac[dt] = __builtin_amdgcn_mfma_f32_16x16x32_bf16(al[s], bh, ac[dt], 0, 0, 0);
                }
            }
        }
    }
    #pragma unroll
    for (int dt = 0; dt < 4; ++dt)
        #pragma unroll
        for (int qq = 0; qq < 4; ++qq)
            fl[w][kg * 4 + qq][dt * 16 + r16] = ac[dt][qq];
    __syncthreads();
    {
        const int row = t >> 4, c = t & 15, grow = base + row;
        const int uid = users[grow], iid = items[grow];
        const f32x4 uv = ld4<FP32>(uemb_, (size_t)uid * DIM + c * 4);
        const f32x4 iv = ld4<FP32>(eemb_, (size_t)iid * DIM + c * 4);
        const f32x4 bv = ld4<FP32>(b_, (size_t)c * 4);
        float p1 = 0.f, p2 = 0.f;
        #pragma unroll
        for (int j = 0; j < 4; ++j) {
            const int d = c * 4 + j;
            const float lg = fl[0][row][d] + fl[1][row][d] + fl[2][row][d] + fl[3][row][d] + bv[j];
            p2 += uv[j] * (1.f / (1.f + expf(-lg)));
            p1 += uv[j] * iv[j];
        }
        #pragma unroll
        for (int m = 1; m < 16; m <<= 1) {
            p1 += __shfl_xor(p1, m, 16);
            p2 += __shfl_xor(p2, m, 16);
        }
        if (c == 0) {
            const float y  = ldT<FP32>(label_, grow);
            const float pa = 1.f / (1.f + expf(-p1));
            const float pb = 1.f / (1.f + expf(-p2));
            st[row] =
                  y * fmaxf(logf(pa), -100.f) + (1.f - y) * fmaxf(log1pf(-pa), -100.f)
                + y * fmaxf(logf(pb), -100.f) + (1.f - y) * fmaxf(log1pf(-pb), -100.f);
        }
    }
    __syncthreads();
    if (t < 64) {
        float s = (t < 16) ? st[t] : 0.f;
        #pragma unroll
        for (int m = 1; m < 64; m <<= 1) s += __shfl_xor(s, m, 64);
        if (t == 0) {
            if (bsum) bsum[blockIdx.x] = (double)s;
            else      atomicAdd(acc, (double)s);
        }
    }
}

__global__ void kgnn_fin(const double* __restrict__ acc, const double* __restrict__ bsum,
                         const int* __restrict__ flag, void* __restrict__ out,
                         const int mode) {
    __shared__ double sd[4];
    const int t = threadIdx.x;
    double s = 0.0;
    if (bsum) {
        for (int i = t; i < EPB; i += 256) s += bsum[i];
    } else if (t == 0) {
        s = *acc;
    }
    #pragma unroll
    for (int m = 1; m < 64; m <<= 1) s += __shfl_xor(s, m, 64);
    if ((t & 63) == 0) sd[t >> 6] = s;
    __syncthreads();
    if (t == 0) {
        const double tot = sd[0] + sd[1] + sd[2] + sd[3];
        const int md = (mode < 0) ? *flag : mode;
        const float loss = (float)(-tot / (double)BATCH);
        if (md) ((float*)out)[0] = loss;
        else    ((__hip_bfloat16*)out)[0] = __float2bfloat16(loss);
    }
}

extern "C" void kernel_launch(void* const* d_in, const int* in_sizes, int n_in,
                              void* d_out, int out_size, void* d_ws, size_t ws_size,
                              hipStream_t stream) {
    const int* users = (const int*)d_in[0];
    const int* items = (const int*)d_in[1];
    const void* label = d_in[2];
    const int* nrel  = (const int*)d_in[3];
    const int* ntail = (const int*)d_in[4];
    const void* uemb = d_in[5];
    const void* eemb = d_in[6];
    const void* remb = d_in[7];
    const void* genW = d_in[8];
    const void* genb = d_in[9];

    double* acc  = (double*)d_ws;
    int*    flag = (int*)((char*)d_ws + 8);
    double* bsum = (ws_size >= (size_t)(1024 + EPB * 8)) ? (double*)((char*)d_ws + 1024)
                                                         : nullptr;
    float*  part = (float*)((char*)d_ws + 16384);
    const size_t needB = 16384 + (size_t)BATCH * 8  * 64 * 4;   // ~33.6 MB
    const size_t needF = 16384 + (size_t)BATCH * 16 * 64 * 4;   // ~67.1 MB
    hipMemsetAsync(d_ws, 0, 16, stream);

    const bool f32sz  = (out_size == 4) && (in_sizes[5] == 128000000);
    const bool bf16sz = (out_size == 2) && (in_sizes[5] == 64000000);

    if (f32sz && bsum && ws_size >= needF) {
        kgnn_part<true><<<(BATCH / RPB) * 16, 512, 0, stream>>>(
            nrel, ntail, eemb, remb, genW, part, flag, 1);
        kgnn_epi<true><<<EPB, 256, 0, stream>>>(
            users, items, label, uemb, eemb, genb, part, bsum, flag, 1);
        kgnn_fin<<<1, 256, 0, stream>>>(acc, bsum, flag, d_out, 1);
    } else if (bf16sz && bsum && ws_size >= needB) {
        kgnn_part<false><<<(BATCH / RPB) * 8, 512, 0, stream>>>(
            nrel, ntail, eemb, remb, genW, part, flag, 0);
        kgnn_epi<false><<<EPB, 256, 0, stream>>>(
            users, items, label, uemb, eemb, genb, part, bsum, flag, 0);
        kgnn_fin<<<1, 256, 0, stream>>>(acc, bsum, flag, d_out, 0);
    } else if (f32sz) {
        kgnn_fb<true><<<EPB, 256, 0, stream>>>(
            users, items, label, nrel, ntail, uemb, eemb, remb, genW, genb,
            acc, bsum, flag, 1);
        kgnn_fin<<<1, 256, 0, stream>>>(acc, bsum, flag, d_out, 1);
    } else if (bf16sz) {
        kgnn_fb<false><<<EPB, 256, 0, stream>>>(
            users, items, label, nrel, ntail, uemb, eemb, remb, genW, genb,
            acc, bsum, flag, 0);
        kgnn_fin<<<1, 256, 0, stream>>>(acc, bsum, flag, d_out, 0);
    } else {
        kgnn_probe<<<1, 64, 0, stream>>>((const unsigned int*)label, flag);
        if (bsum && ws_size >= needF) {
            kgnn_part<false><<<(BATCH / RPB) * 8, 512, 0, stream>>>(
                nrel, ntail, eemb, remb, genW, part, flag, -1);
            kgnn_part<true><<<(BATCH / RPB) * 16, 512, 0, stream>>>(
                nrel, ntail, eemb, remb, genW, part, flag, -1);
            kgnn_epi<false><<<EPB, 256, 0, stream>>>(
                users, items, label, uemb, eemb, genb, part, bsum, flag, -1);
            kgnn_epi<true><<<EPB, 256, 0, stream>>>(
                users, items, label, uemb, eemb, genb, part, bsum, flag, -1);
        } else {
            kgnn_fb<false><<<EPB, 256, 0, stream>>>(
                users, items, label, nrel, ntail, uemb, eemb, remb, genW, genb,
                acc, bsum, flag, -1);
            kgnn_fb<true><<<EPB, 256, 0, stream>>>(
                users, items, label, nrel, ntail, uemb, eemb, remb, genW, genb,
                acc, bsum, flag, -1);
        }
        kgnn_fin<<<1, 256, 0, stream>>>(acc, bsum, flag, d_out, -1);
    }
}